// Round 12
// baseline (59.770 us; speedup 1.0000x reference)
//
#include <hip/hip_runtime.h>
#include <hip/hip_bf16.h>
#include <stdint.h>

#define LOG2E 1.4426950408889634f
#define SEQ 4096
#define DIN 512
#define DH 64
#define NSPLIT 16
#define QSCALE (0.125f * LOG2E)

typedef __attribute__((ext_vector_type(8))) short short8;
typedef __attribute__((ext_vector_type(16))) float f32x16;
typedef __attribute__((ext_vector_type(4))) float f32x4;

static __device__ __forceinline__ uint16_t f2bf(float f){
  uint32_t u = __float_as_uint(f);
  uint32_t r = u + 0x7fffu + ((u >> 16) & 1u);
  return (uint16_t)(r >> 16);
}

static __device__ __forceinline__ uint32_t cvt_pk_bf16(float lo, float hi){
  uint32_t d;
  asm("v_cvt_pk_bf16_f32 %0, %1, %2" : "=v"(d) : "v"(lo), "v"(hi));
  return d;
}

static __device__ __forceinline__ void perm32swap(uint32_t &a, uint32_t &b){
  asm("v_permlane32_swap_b32 %0, %1" : "+v"(a), "+v"(b));
}

static __device__ __forceinline__ float xadd32(float v){ return v + __shfl_xor(v, 32); }

static __device__ __forceinline__ void gload_lds16(const void* g, void* l){
  __builtin_amdgcn_global_load_lds(
      (const __attribute__((address_space(1))) unsigned int*)g,
      (__attribute__((address_space(3))) unsigned int*)l, 16, 0, 0);
}

// ---------------- kernel 1: pack W into MFMA B-fragment order (bf16) ----------------
__global__ void packw_kernel(const float* __restrict__ Wq, const float* __restrict__ Wk,
                             const float* __restrict__ Wv, uint4* __restrict__ Wp){
  int t0 = blockIdx.x * 256 + threadIdx.x;   // 0..12287
  int lane = t0 & 63;
  int grp = t0 >> 6;                          // 0..191
  int w3 = grp >> 6;
  int t  = (grp >> 2) & 15;
  int nc = grp & 3;
  const float* W = (w3 == 0) ? Wq : ((w3 == 1) ? Wk : Wv);
  int g = lane >> 4, cc = lane & 15;
  int k0 = t * 32 + g * 8;
  int n  = nc * 16 + cc;
  uint32_t o[4];
  #pragma unroll
  for (int p = 0; p < 4; ++p){
    float lo = W[(size_t)(k0 + 2*p    ) * DH + n];
    float hi = W[(size_t)(k0 + 2*p + 1) * DH + n];
    o[p] = cvt_pk_bf16(lo, hi);
  }
  Wp[(size_t)grp * 64 + lane] = make_uint4(o[0], o[1], o[2], o[3]);
}

// ---------------- kernel 2: QKV projection (512 blocks, 32 rows; x staged once in LDS) ----------------
__global__ __launch_bounds__(256) void proj_kernel(
    const float* __restrict__ x, const uint4* __restrict__ Wp,
    const float* __restrict__ bq, const float* __restrict__ bk, const float* __restrict__ bv,
    uint16_t* __restrict__ Qs, uint16_t* __restrict__ Kb, uint16_t* __restrict__ Vt)
{
  __shared__ uint16_t xl[32][520];   // 512 cols + 8 pad
  int tid = threadIdx.x, lane = tid & 63, wv = tid >> 6;
  int c = lane & 15, g = lane >> 4;
  int rowbase = blockIdx.x * 32;

  {
    int row = tid >> 3, cb = (tid & 7) * 64;
    const float* src = x + (size_t)(rowbase + row) * DIN + cb;
    #pragma unroll
    for (int i = 0; i < 4; ++i){
      float4 f0 = *(const float4*)(src + i * 16 + 0);
      float4 f1 = *(const float4*)(src + i * 16 + 4);
      float4 f2 = *(const float4*)(src + i * 16 + 8);
      float4 f3 = *(const float4*)(src + i * 16 + 12);
      uint4 w0 = make_uint4(cvt_pk_bf16(f0.x, f0.y), cvt_pk_bf16(f0.z, f0.w),
                            cvt_pk_bf16(f1.x, f1.y), cvt_pk_bf16(f1.z, f1.w));
      uint4 w1 = make_uint4(cvt_pk_bf16(f2.x, f2.y), cvt_pk_bf16(f2.z, f2.w),
                            cvt_pk_bf16(f3.x, f3.y), cvt_pk_bf16(f3.z, f3.w));
      *(uint4*)(&xl[row][cb + i * 16]) = w0;
      *(uint4*)(&xl[row][cb + i * 16 + 8]) = w1;
    }
  }
  __syncthreads();

  f32x4 acc[2][3];
  #pragma unroll
  for (int mt = 0; mt < 2; ++mt)
    #pragma unroll
    for (int j = 0; j < 3; ++j)
      #pragma unroll
      for (int r = 0; r < 4; ++r) acc[mt][j][r] = 0.f;

  #pragma unroll 2
  for (int t = 0; t < 16; ++t){
    short8 xa[2];
    #pragma unroll
    for (int mt = 0; mt < 2; ++mt)
      xa[mt] = *(const short8*)(&xl[mt * 16 + c][t * 32 + g * 8]);
    #pragma unroll
    for (int j = 0; j < 3; ++j){
      int i = wv * 3 + j;
      union { uint4 u; short8 s; } wf;
      wf.u = Wp[(size_t)((i >> 2) * 64 + t * 4 + (i & 3)) * 64 + lane];
      #pragma unroll
      for (int mt = 0; mt < 2; ++mt)
        acc[mt][j] = __builtin_amdgcn_mfma_f32_16x16x32_bf16(xa[mt], wf.s, acc[mt][j], 0, 0, 0);
    }
  }

  #pragma unroll
  for (int mt = 0; mt < 2; ++mt){
    int mb0 = rowbase + mt * 16 + 4 * g;
    #pragma unroll
    for (int j = 0; j < 3; ++j){
      int i = wv * 3 + j;
      int w3 = i >> 2, nc = i & 3, n = nc * 16 + c;
      const float* B = (w3 == 0) ? bq : ((w3 == 1) ? bk : bv);
      float bias = B[n];
      float v0 = acc[mt][j][0] + bias;
      float v1 = acc[mt][j][1] + bias;
      float v2 = acc[mt][j][2] + bias;
      float v3 = acc[mt][j][3] + bias;
      if (w3 == 0){
        Qs[(size_t)(mb0 + 0) * DH + n] = f2bf(v0 * QSCALE);
        Qs[(size_t)(mb0 + 1) * DH + n] = f2bf(v1 * QSCALE);
        Qs[(size_t)(mb0 + 2) * DH + n] = f2bf(v2 * QSCALE);
        Qs[(size_t)(mb0 + 3) * DH + n] = f2bf(v3 * QSCALE);
      } else if (w3 == 1){
        Kb[(size_t)(mb0 + 0) * DH + n] = f2bf(v0);
        Kb[(size_t)(mb0 + 1) * DH + n] = f2bf(v1);
        Kb[(size_t)(mb0 + 2) * DH + n] = f2bf(v2);
        Kb[(size_t)(mb0 + 3) * DH + n] = f2bf(v3);
      } else {
        int b = mb0 >> 12, mloc = mb0 & 4095;
        uint32_t lo = cvt_pk_bf16(v0, v1);
        uint32_t hi = cvt_pk_bf16(v2, v3);
        *(uint2*)(&Vt[((size_t)(b * DH + n)) * SEQ + mloc]) = make_uint2(lo, hi);
      }
    }
  }
}

// ---------------- kernel 3: flash attention, KV-split=16, stage-once, BARRIER-FREE main loop ----------------
__global__ __launch_bounds__(256, 2) void attn_kernel(
    const uint16_t* __restrict__ Qs, const uint16_t* __restrict__ Kb,
    const uint16_t* __restrict__ Vt, uint16_t* __restrict__ Pacc,
    float* __restrict__ Pl)
{
  __shared__ uint8_t lds[65536];   // K: 4 tiles x 8KB | V: 4 tiles x 8KB
  const int tid = threadIdx.x, lane = tid & 63, wv = tid >> 6;
  const int bid = blockIdx.x;
  const int split = bid & 15, batch = (bid >> 4) & 3, qtile = bid >> 6; // 0..31
  const int c = lane & 31, hi = lane >> 5;
  const int NT = SEQ / NSPLIT / 64;  // 4 tiles of 64 keys

  const int qrow = batch * SEQ + qtile * 128 + wv * 32 + c;

  short8 qf[4];
  {
    const uint16_t* qp = Qs + (size_t)qrow * DH;
    #pragma unroll
    for (int ks = 0; ks < 4; ++ks){
      union { uint4 u; short8 s; } v;
      v.u = *(const uint4*)(qp + ks * 16 + hi * 8);
      qf[ks] = v.s;
    }
  }

  // hoisted swizzled LDS read addresses (shared by K and V paths)
  int addr8[2][4];
  #pragma unroll
  for (int a = 0; a < 2; ++a)
    #pragma unroll
    for (int b = 0; b < 4; ++b)
      addr8[a][b] = (32 * a + c) * 128 + (((2 * b + hi) ^ (c & 7)) << 4);

  const uint8_t* Kg = (const uint8_t*)Kb + ((size_t)(batch * SEQ + split * 256)) * (DH * 2);
  const uint8_t* Vg = (const uint8_t*)Vt + (size_t)batch * (DH * SEQ * 2) + split * 512;

  // ---- stage the ENTIRE 64KB K/V slice once (swizzled source -> linear LDS) ----
  #pragma unroll
  for (int pass = 0; pass < 8; ++pass){
    int s = pass * 256 + tid;              // 0..2047
    int key = s >> 3, dg = (s & 7) ^ (key & 7);
    gload_lds16(Kg + key * 128 + dg * 16, lds + pass * 4096 + wv * 1024);
  }
  #pragma unroll
  for (int pass = 0; pass < 8; ++pass){
    int s = pass * 256 + tid;              // 0..2047
    int t4 = s >> 9, r = (s >> 3) & 63, j = s & 7;
    gload_lds16(Vg + (size_t)r * (SEQ * 2) + t4 * 128 + ((j ^ (r & 7)) << 4),
                lds + 32768 + pass * 4096 + wv * 1024);
  }
  asm volatile("s_waitcnt vmcnt(0)" ::: "memory");
  __syncthreads();
  // ---- from here on: no barriers, no staging — waves fully independent ----

  f32x16 acc[2];
  #pragma unroll
  for (int d = 0; d < 2; ++d)
    #pragma unroll
    for (int r = 0; r < 16; ++r) acc[d][r] = 0.f;

  f32x16 ZERO;
  #pragma unroll
  for (int r = 0; r < 16; ++r) ZERO[r] = 0.f;
  asm volatile("" : "+v"(ZERO));

  float l0_ = 0.f, l1_ = 0.f, l2_ = 0.f, l3_ = 0.f;

  #pragma unroll 1
  for (int t = 0; t < NT; ++t){
    const int OFF = t << 13;   // t * 8192

    // S^T = K * Q^T; first ks uses ZERO as C
    f32x16 sa[2];
    __builtin_amdgcn_s_setprio(1);
    #pragma unroll
    for (int st = 0; st < 2; ++st){
      #pragma unroll
      for (int ks = 0; ks < 4; ++ks){
        short8 kf = *(const short8*)(lds + OFF + addr8[st][ks]);
        sa[st] = __builtin_amdgcn_mfma_f32_32x32x16_bf16(
            kf, qf[ks], (ks == 0) ? ZERO : sa[st], 0, 0, 0);
      }
    }
    __builtin_amdgcn_s_setprio(0);

    // softmax: raw v_exp_f32 (log2-domain scores), 4-way partial sums
    uint32_t pk[2][8];
    #pragma unroll
    for (int st = 0; st < 2; ++st){
      float pv[16];
      #pragma unroll
      for (int r = 0; r < 16; ++r) pv[r] = __builtin_amdgcn_exp2f(sa[st][r]);
      #pragma unroll
      for (int r = 0; r < 4; ++r){
        l0_ += pv[4 * r + 0];
        l1_ += pv[4 * r + 1];
        l2_ += pv[4 * r + 2];
        l3_ += pv[4 * r + 3];
      }
      #pragma unroll
      for (int p = 0; p < 8; ++p) pk[st][p] = cvt_pk_bf16(pv[2 * p], pv[2 * p + 1]);
    }

    // P^T B-fragments
    short8 pf[4];
    #pragma unroll
    for (int kslab = 0; kslab < 4; ++kslab){
      int st = kslab >> 1, q4 = (kslab & 1) * 4;
      uint32_t w_[4];
      #pragma unroll
      for (int w1 = 0; w1 < 2; ++w1){
        uint32_t a = pk[st][q4 + w1];
        uint32_t b = pk[st][q4 + 2 + w1];
        perm32swap(a, b);
        w_[w1] = a; w_[2 + w1] = b;
      }
      union { uint32_t u[4]; short8 s; } u_;
      u_.u[0] = w_[0]; u_.u[1] = w_[1]; u_.u[2] = w_[2]; u_.u[3] = w_[3];
      pf[kslab] = u_.s;
    }

    // out^T += Vt * P^T
    __builtin_amdgcn_s_setprio(1);
    #pragma unroll
    for (int kslab = 0; kslab < 4; ++kslab){
      #pragma unroll
      for (int dst = 0; dst < 2; ++dst){
        short8 vf = *(const short8*)(lds + 32768 + OFF + addr8[dst][kslab]);
        acc[dst] = __builtin_amdgcn_mfma_f32_32x32x16_bf16(vf, pf[kslab], acc[dst], 0, 0, 0);
      }
    }
    __builtin_amdgcn_s_setprio(0);
  }

  // store bf16 partials
  uint16_t* pa = Pacc + ((size_t)split * 16384 + qrow) * DH;
  #pragma unroll
  for (int dst = 0; dst < 2; ++dst)
    #pragma unroll
    for (int rq = 0; rq < 4; ++rq){
      uint32_t lo = cvt_pk_bf16(acc[dst][rq * 4 + 0], acc[dst][rq * 4 + 1]);
      uint32_t hi2 = cvt_pk_bf16(acc[dst][rq * 4 + 2], acc[dst][rq * 4 + 3]);
      *(uint2*)(pa + dst * 32 + rq * 8 + hi * 4) = make_uint2(lo, hi2);
    }
  float l_tot = xadd32((l0_ + l1_) + (l2_ + l3_));
  if (hi == 0) Pl[(size_t)split * 16384 + qrow] = l_tot;
}

// ---------------- kernel 4: combine the 16 KV-split partials (512 blocks, 8 d/thread) ----------------
__global__ __launch_bounds__(256) void combine_kernel(
    const uint16_t* __restrict__ Pacc, const float* __restrict__ Pl,
    float* __restrict__ out)
{
  int t = blockIdx.x * 256 + threadIdx.x;    // 0..131071
  int q = t >> 3, part = t & 7;              // 8 d-values each
  float l = 0.f;
  #pragma unroll
  for (int s = 0; s < NSPLIT; ++s) l += Pl[(size_t)s * 16384 + q];
  float inv = 1.0f / l;

  float o[8];
  #pragma unroll
  for (int i = 0; i < 8; ++i) o[i] = 0.f;
  #pragma unroll
  for (int s = 0; s < NSPLIT; ++s){
    const uint16_t* p = Pacc + ((size_t)s * 16384 + q) * DH + part * 8;
    uint4 v = *(const uint4*)(p);
    const uint32_t* w = (const uint32_t*)&v;
    #pragma unroll
    for (int k = 0; k < 4; ++k){
      o[2 * k + 0] += __uint_as_float((w[k] & 0xffffu) << 16);
      o[2 * k + 1] += __uint_as_float((w[k] >> 16) << 16);
    }
  }
  float* ob = out + (size_t)q * DH + part * 8;
  #pragma unroll
  for (int i = 0; i < 2; ++i){
    float4 v = make_float4(o[4*i] * inv, o[4*i+1] * inv, o[4*i+2] * inv, o[4*i+3] * inv);
    *(float4*)(ob + 4 * i) = v;
  }
}

extern "C" void kernel_launch(void* const* d_in, const int* in_sizes, int n_in,
                              void* d_out, int out_size, void* d_ws, size_t ws_size,
                              hipStream_t stream)
{
  (void)in_sizes; (void)n_in; (void)out_size; (void)ws_size;
  const float* x  = (const float*)d_in[0];
  const float* Wq = (const float*)d_in[1];
  const float* bq = (const float*)d_in[2];
  const float* Wk = (const float*)d_in[3];
  const float* bk = (const float*)d_in[4];
  const float* Wv = (const float*)d_in[5];
  const float* bv = (const float*)d_in[6];
  float* out = (float*)d_out;
  uint8_t* ws = (uint8_t*)d_ws;

  const size_t o_Wp = 0;                      // 196608 B
  const size_t o_Q  = 196608;                 // 2 MB bf16 [16384][64]
  const size_t o_K  = o_Q + 2097152;          // 2 MB
  const size_t o_Vt = o_K + 2097152;          // 2 MB bf16 [4][64][4096]
  const size_t o_Pa = o_Vt + 2097152;         // 32 MB bf16 [16][16384][64]
  const size_t o_Pl = o_Pa + 33554432;        // 1 MB f32 [16][16384]

  packw_kernel<<<48, 256, 0, stream>>>(Wq, Wk, Wv, (uint4*)(ws + o_Wp));
  proj_kernel<<<512, 256, 0, stream>>>(x, (const uint4*)(ws + o_Wp), bq, bk, bv,
      (uint16_t*)(ws + o_Q), (uint16_t*)(ws + o_K), (uint16_t*)(ws + o_Vt));
  attn_kernel<<<2048, 256, 0, stream>>>((const uint16_t*)(ws + o_Q), (const uint16_t*)(ws + o_K),
      (const uint16_t*)(ws + o_Vt), (uint16_t*)(ws + o_Pa), (float*)(ws + o_Pl));
  combine_kernel<<<512, 256, 0, stream>>>((const uint16_t*)(ws + o_Pa), (const float*)(ws + o_Pl), out);
}

// Round 13
// 53.523 us; speedup vs baseline: 1.1167x; 1.1167x over previous
//
#include <hip/hip_runtime.h>
#include <hip/hip_bf16.h>
#include <stdint.h>

#define LOG2E 1.4426950408889634f
#define SEQ 4096
#define DIN 512
#define DH 64
#define NSPLIT 8
#define QSCALE (0.125f * LOG2E)

typedef __attribute__((ext_vector_type(8))) short short8;
typedef __attribute__((ext_vector_type(16))) float f32x16;
typedef __attribute__((ext_vector_type(4))) float f32x4;

static __device__ __forceinline__ uint16_t f2bf(float f){
  uint32_t u = __float_as_uint(f);
  uint32_t r = u + 0x7fffu + ((u >> 16) & 1u);
  return (uint16_t)(r >> 16);
}

static __device__ __forceinline__ uint32_t cvt_pk_bf16(float lo, float hi){
  uint32_t d;
  asm("v_cvt_pk_bf16_f32 %0, %1, %2" : "=v"(d) : "v"(lo), "v"(hi));
  return d;
}

static __device__ __forceinline__ void perm32swap(uint32_t &a, uint32_t &b){
  asm("v_permlane32_swap_b32 %0, %1" : "+v"(a), "+v"(b));
}

static __device__ __forceinline__ float xadd32(float v){ return v + __shfl_xor(v, 32); }

static __device__ __forceinline__ void gload_lds16(const void* g, void* l){
  __builtin_amdgcn_global_load_lds(
      (const __attribute__((address_space(1))) unsigned int*)g,
      (__attribute__((address_space(3))) unsigned int*)l, 16, 0, 0);
}

// ---------------- kernel 1: pack W into MFMA B-fragment order (bf16) ----------------
__global__ void packw_kernel(const float* __restrict__ Wq, const float* __restrict__ Wk,
                             const float* __restrict__ Wv, uint4* __restrict__ Wp){
  int t0 = blockIdx.x * 256 + threadIdx.x;   // 0..12287
  int lane = t0 & 63;
  int grp = t0 >> 6;                          // 0..191
  int w3 = grp >> 6;
  int t  = (grp >> 2) & 15;
  int nc = grp & 3;
  const float* W = (w3 == 0) ? Wq : ((w3 == 1) ? Wk : Wv);
  int g = lane >> 4, cc = lane & 15;
  int k0 = t * 32 + g * 8;
  int n  = nc * 16 + cc;
  uint32_t o[4];
  #pragma unroll
  for (int p = 0; p < 4; ++p){
    float lo = W[(size_t)(k0 + 2*p    ) * DH + n];
    float hi = W[(size_t)(k0 + 2*p + 1) * DH + n];
    o[p] = cvt_pk_bf16(lo, hi);
  }
  Wp[(size_t)grp * 64 + lane] = make_uint4(o[0], o[1], o[2], o[3]);
}

// ---------------- kernel 2: QKV projection (1024 blocks x 16 rows; x staged once in LDS) ----------------
__global__ __launch_bounds__(256, 4) void proj_kernel(
    const float* __restrict__ x, const uint4* __restrict__ Wp,
    const float* __restrict__ bq, const float* __restrict__ bk, const float* __restrict__ bv,
    uint16_t* __restrict__ Qs, uint16_t* __restrict__ Kb, uint16_t* __restrict__ Vt)
{
  __shared__ uint16_t xl[16][520];   // 512 cols + 8 pad
  int tid = threadIdx.x, lane = tid & 63, wv = tid >> 6;
  int c = lane & 15, g = lane >> 4;
  int rowbase = blockIdx.x * 16;

  // stage x tile once: thread handles row=tid>>4, 32 cols starting (tid&15)*32
  {
    int row = tid >> 4, cb = (tid & 15) * 32;
    const float* src = x + (size_t)(rowbase + row) * DIN + cb;
    #pragma unroll
    for (int i = 0; i < 2; ++i){
      float4 f0 = *(const float4*)(src + i * 16 + 0);
      float4 f1 = *(const float4*)(src + i * 16 + 4);
      float4 f2 = *(const float4*)(src + i * 16 + 8);
      float4 f3 = *(const float4*)(src + i * 16 + 12);
      uint4 w0 = make_uint4(cvt_pk_bf16(f0.x, f0.y), cvt_pk_bf16(f0.z, f0.w),
                            cvt_pk_bf16(f1.x, f1.y), cvt_pk_bf16(f1.z, f1.w));
      uint4 w1 = make_uint4(cvt_pk_bf16(f2.x, f2.y), cvt_pk_bf16(f2.z, f2.w),
                            cvt_pk_bf16(f3.x, f3.y), cvt_pk_bf16(f3.z, f3.w));
      *(uint4*)(&xl[row][cb + i * 16]) = w0;
      *(uint4*)(&xl[row][cb + i * 16 + 8]) = w1;
    }
  }
  __syncthreads();

  f32x4 acc[3];
  #pragma unroll
  for (int j = 0; j < 3; ++j)
    #pragma unroll
    for (int r = 0; r < 4; ++r) acc[j][r] = 0.f;

  #pragma unroll 4
  for (int t = 0; t < 16; ++t){
    short8 xa = *(const short8*)(&xl[c][t * 32 + g * 8]);
    #pragma unroll
    for (int j = 0; j < 3; ++j){
      int i = wv * 3 + j;
      union { uint4 u; short8 s; } wf;
      wf.u = Wp[(size_t)((i >> 2) * 64 + t * 4 + (i & 3)) * 64 + lane];
      acc[j] = __builtin_amdgcn_mfma_f32_16x16x32_bf16(xa, wf.s, acc[j], 0, 0, 0);
    }
  }

  int mb0 = rowbase + 4 * g;
  #pragma unroll
  for (int j = 0; j < 3; ++j){
    int i = wv * 3 + j;
    int w3 = i >> 2, nc = i & 3, n = nc * 16 + c;
    const float* B = (w3 == 0) ? bq : ((w3 == 1) ? bk : bv);
    float bias = B[n];
    float v0 = acc[j][0] + bias;
    float v1 = acc[j][1] + bias;
    float v2 = acc[j][2] + bias;
    float v3 = acc[j][3] + bias;
    if (w3 == 0){
      Qs[(size_t)(mb0 + 0) * DH + n] = f2bf(v0 * QSCALE);
      Qs[(size_t)(mb0 + 1) * DH + n] = f2bf(v1 * QSCALE);
      Qs[(size_t)(mb0 + 2) * DH + n] = f2bf(v2 * QSCALE);
      Qs[(size_t)(mb0 + 3) * DH + n] = f2bf(v3 * QSCALE);
    } else if (w3 == 1){
      Kb[(size_t)(mb0 + 0) * DH + n] = f2bf(v0);
      Kb[(size_t)(mb0 + 1) * DH + n] = f2bf(v1);
      Kb[(size_t)(mb0 + 2) * DH + n] = f2bf(v2);
      Kb[(size_t)(mb0 + 3) * DH + n] = f2bf(v3);
    } else {
      int b = mb0 >> 12, mloc = mb0 & 4095;
      uint32_t lo = cvt_pk_bf16(v0, v1);
      uint32_t hi = cvt_pk_bf16(v2, v3);
      *(uint2*)(&Vt[((size_t)(b * DH + n)) * SEQ + mloc]) = make_uint2(lo, hi);
    }
  }
}

// ---------------- kernel 3: flash attention, KV-split=8, 1 q-group, VALU-lean (R5/R11 exact) ----------------
__global__ __launch_bounds__(256, 3) void attn_kernel(
    const uint16_t* __restrict__ Qs, const uint16_t* __restrict__ Kb,
    const uint16_t* __restrict__ Vt, uint16_t* __restrict__ Pacc,
    float* __restrict__ Pl)
{
  __shared__ uint8_t lds[32768];   // [buf][K 8KB | Vt 8KB]
  const int tid = threadIdx.x, lane = tid & 63, wv = tid >> 6;
  const int bid = blockIdx.x;
  const int split = bid & 7, batch = (bid >> 3) & 3, qtile = bid >> 5; // 0..31
  const int c = lane & 31, hi = lane >> 5;
  const int NT = SEQ / NSPLIT / 64;  // 8 tiles of 64 keys

  const int qrow = batch * SEQ + qtile * 128 + wv * 32 + c;

  short8 qf[4];
  {
    const uint16_t* qp = Qs + (size_t)qrow * DH;
    #pragma unroll
    for (int ks = 0; ks < 4; ++ks){
      union { uint4 u; short8 s; } v;
      v.u = *(const uint4*)(qp + ks * 16 + hi * 8);
      qf[ks] = v.s;
    }
  }

  // hoisted swizzled LDS read addresses (shared by K and V paths)
  int addr8[2][4];
  #pragma unroll
  for (int a = 0; a < 2; ++a)
    #pragma unroll
    for (int b = 0; b < 4; ++b)
      addr8[a][b] = (32 * a + c) * 128 + (((2 * b + hi) ^ (c & 7)) << 4);

  // staging source addresses (swizzled source -> linear LDS dest)
  const int slotA = wv * 128 + lane, slotB = slotA + 64;
  const int keyA = slotA >> 3, keyB = slotB >> 3;
  const int dgA = (slotA & 7) ^ (keyA & 7), dgB = (slotB & 7) ^ (keyB & 7);
  const uint8_t* Kg = (const uint8_t*)Kb + ((size_t)(batch * SEQ + split * 512)) * (DH * 2);
  const uint8_t* KgA = Kg + keyA * 128 + dgA * 16;
  const uint8_t* KgB = Kg + keyB * 128 + dgB * 16;
  const uint8_t* Vg = (const uint8_t*)Vt + (size_t)batch * (DH * SEQ * 2) + split * 1024;
  const uint8_t* VgA = Vg + keyA * (SEQ * 2) + dgA * 16;
  const uint8_t* VgB = Vg + keyB * (SEQ * 2) + dgB * 16;

  f32x16 acc[2];
  #pragma unroll
  for (int d = 0; d < 2; ++d)
    #pragma unroll
    for (int r = 0; r < 16; ++r) acc[d][r] = 0.f;

  f32x16 ZERO;
  #pragma unroll
  for (int r = 0; r < 16; ++r) ZERO[r] = 0.f;
  asm volatile("" : "+v"(ZERO));

  float l0_ = 0.f, l1_ = 0.f, l2_ = 0.f, l3_ = 0.f;

  gload_lds16(KgA, lds + wv * 2048);
  gload_lds16(KgB, lds + wv * 2048 + 1024);
  gload_lds16(VgA, lds + 8192 + wv * 2048);
  gload_lds16(VgB, lds + 8192 + wv * 2048 + 1024);
  __syncthreads();

  #pragma unroll 1
  for (int t = 0; t < NT; ++t){
    const int OFF = (t & 1) << 14;
    const int NOFF = OFF ^ 16384;

    if (t < NT - 1){
      gload_lds16(KgA + (size_t)(t + 1) * 8192, lds + NOFF + wv * 2048);
      gload_lds16(KgB + (size_t)(t + 1) * 8192, lds + NOFF + wv * 2048 + 1024);
      gload_lds16(VgA + (size_t)(t + 1) * 128,  lds + NOFF + 8192 + wv * 2048);
      gload_lds16(VgB + (size_t)(t + 1) * 128,  lds + NOFF + 8192 + wv * 2048 + 1024);
    }

    // S^T = K * Q^T; first ks uses ZERO as C
    f32x16 sa[2];
    __builtin_amdgcn_s_setprio(1);
    #pragma unroll
    for (int st = 0; st < 2; ++st){
      #pragma unroll
      for (int ks = 0; ks < 4; ++ks){
        short8 kf = *(const short8*)(lds + OFF + addr8[st][ks]);
        sa[st] = __builtin_amdgcn_mfma_f32_32x32x16_bf16(
            kf, qf[ks], (ks == 0) ? ZERO : sa[st], 0, 0, 0);
      }
    }
    __builtin_amdgcn_s_setprio(0);

    // softmax: raw v_exp_f32 (log2-domain scores), 4-way partial sums
    uint32_t pk[2][8];
    #pragma unroll
    for (int st = 0; st < 2; ++st){
      float pv[16];
      #pragma unroll
      for (int r = 0; r < 16; ++r) pv[r] = __builtin_amdgcn_exp2f(sa[st][r]);
      #pragma unroll
      for (int r = 0; r < 4; ++r){
        l0_ += pv[4 * r + 0];
        l1_ += pv[4 * r + 1];
        l2_ += pv[4 * r + 2];
        l3_ += pv[4 * r + 3];
      }
      #pragma unroll
      for (int p = 0; p < 8; ++p) pk[st][p] = cvt_pk_bf16(pv[2 * p], pv[2 * p + 1]);
    }

    // P^T B-fragments
    short8 pf[4];
    #pragma unroll
    for (int kslab = 0; kslab < 4; ++kslab){
      int st = kslab >> 1, q4 = (kslab & 1) * 4;
      uint32_t w_[4];
      #pragma unroll
      for (int w1 = 0; w1 < 2; ++w1){
        uint32_t a = pk[st][q4 + w1];
        uint32_t b = pk[st][q4 + 2 + w1];
        perm32swap(a, b);
        w_[w1] = a; w_[2 + w1] = b;
      }
      union { uint32_t u[4]; short8 s; } u_;
      u_.u[0] = w_[0]; u_.u[1] = w_[1]; u_.u[2] = w_[2]; u_.u[3] = w_[3];
      pf[kslab] = u_.s;
    }

    // out^T += Vt * P^T
    __builtin_amdgcn_s_setprio(1);
    #pragma unroll
    for (int kslab = 0; kslab < 4; ++kslab){
      #pragma unroll
      for (int dst = 0; dst < 2; ++dst){
        short8 vf = *(const short8*)(lds + OFF + 8192 + addr8[dst][kslab]);
        acc[dst] = __builtin_amdgcn_mfma_f32_32x32x16_bf16(vf, pf[kslab], acc[dst], 0, 0, 0);
      }
    }
    __builtin_amdgcn_s_setprio(0);

    __syncthreads();
  }

  // store bf16 partials
  uint16_t* pa = Pacc + ((size_t)split * 16384 + qrow) * DH;
  #pragma unroll
  for (int dst = 0; dst < 2; ++dst)
    #pragma unroll
    for (int rq = 0; rq < 4; ++rq){
      uint32_t lo = cvt_pk_bf16(acc[dst][rq * 4 + 0], acc[dst][rq * 4 + 1]);
      uint32_t hi2 = cvt_pk_bf16(acc[dst][rq * 4 + 2], acc[dst][rq * 4 + 3]);
      *(uint2*)(pa + dst * 32 + rq * 8 + hi * 4) = make_uint2(lo, hi2);
    }
  float l_tot = xadd32((l0_ + l1_) + (l2_ + l3_));
  if (hi == 0) Pl[(size_t)split * 16384 + qrow] = l_tot;
}

// ---------------- kernel 4: combine the 8 KV-split partials (1024 blocks, 4 d/thread) ----------------
__global__ __launch_bounds__(256) void combine_kernel(
    const uint16_t* __restrict__ Pacc, const float* __restrict__ Pl,
    float* __restrict__ out)
{
  int t = blockIdx.x * 256 + threadIdx.x;    // 0..262143
  int q = t >> 4, part = t & 15;             // 4 d-values each
  float l = 0.f;
  #pragma unroll
  for (int s = 0; s < NSPLIT; ++s) l += Pl[(size_t)s * 16384 + q];
  float inv = 1.0f / l;

  float o[4];
  #pragma unroll
  for (int i = 0; i < 4; ++i) o[i] = 0.f;
  #pragma unroll
  for (int s = 0; s < NSPLIT; ++s){
    const uint16_t* p = Pacc + ((size_t)s * 16384 + q) * DH + part * 4;
    uint2 v = *(const uint2*)(p);
    o[0] += __uint_as_float((v.x & 0xffffu) << 16);
    o[1] += __uint_as_float((v.x >> 16) << 16);
    o[2] += __uint_as_float((v.y & 0xffffu) << 16);
    o[3] += __uint_as_float((v.y >> 16) << 16);
  }
  float4 v = make_float4(o[0] * inv, o[1] * inv, o[2] * inv, o[3] * inv);
  *(float4*)(out + (size_t)q * DH + part * 4) = v;
}

extern "C" void kernel_launch(void* const* d_in, const int* in_sizes, int n_in,
                              void* d_out, int out_size, void* d_ws, size_t ws_size,
                              hipStream_t stream)
{
  (void)in_sizes; (void)n_in; (void)out_size; (void)ws_size;
  const float* x  = (const float*)d_in[0];
  const float* Wq = (const float*)d_in[1];
  const float* bq = (const float*)d_in[2];
  const float* Wk = (const float*)d_in[3];
  const float* bk = (const float*)d_in[4];
  const float* Wv = (const float*)d_in[5];
  const float* bv = (const float*)d_in[6];
  float* out = (float*)d_out;
  uint8_t* ws = (uint8_t*)d_ws;

  const size_t o_Wp = 0;                      // 196608 B
  const size_t o_Q  = 196608;                 // 2 MB bf16 [16384][64]
  const size_t o_K  = o_Q + 2097152;          // 2 MB
  const size_t o_Vt = o_K + 2097152;          // 2 MB bf16 [4][64][4096]
  const size_t o_Pa = o_Vt + 2097152;         // 16 MB bf16 [8][16384][64]
  const size_t o_Pl = o_Pa + 16777216;        // 512 KB f32 [8][16384]

  packw_kernel<<<48, 256, 0, stream>>>(Wq, Wk, Wv, (uint4*)(ws + o_Wp));
  proj_kernel<<<1024, 256, 0, stream>>>(x, (const uint4*)(ws + o_Wp), bq, bk, bv,
      (uint16_t*)(ws + o_Q), (uint16_t*)(ws + o_K), (uint16_t*)(ws + o_Vt));
  attn_kernel<<<1024, 256, 0, stream>>>((const uint16_t*)(ws + o_Q), (const uint16_t*)(ws + o_K),
      (const uint16_t*)(ws + o_Vt), (uint16_t*)(ws + o_Pa), (float*)(ws + o_Pl));
  combine_kernel<<<1024, 256, 0, stream>>>((const uint16_t*)(ws + o_Pa), (const float*)(ws + o_Pl), out);
}

// Round 15
// 53.232 us; speedup vs baseline: 1.1228x; 1.0055x over previous
//
#include <hip/hip_runtime.h>
#include <hip/hip_bf16.h>
#include <stdint.h>

#define LOG2E 1.4426950408889634f
#define SEQ 4096
#define DIN 512
#define DH 64
#define NSPLIT 8
#define QSCALE (0.125f * LOG2E)

typedef __attribute__((ext_vector_type(8))) short short8;
typedef __attribute__((ext_vector_type(16))) float f32x16;
typedef __attribute__((ext_vector_type(4))) float f32x4;

static __device__ __forceinline__ uint16_t f2bf(float f){
  uint32_t u = __float_as_uint(f);
  uint32_t r = u + 0x7fffu + ((u >> 16) & 1u);
  return (uint16_t)(r >> 16);
}

static __device__ __forceinline__ uint32_t cvt_pk_bf16(float lo, float hi){
  uint32_t d;
  asm("v_cvt_pk_bf16_f32 %0, %1, %2" : "=v"(d) : "v"(lo), "v"(hi));
  return d;
}

static __device__ __forceinline__ void perm32swap(uint32_t &a, uint32_t &b){
  asm("v_permlane32_swap_b32 %0, %1" : "+v"(a), "+v"(b));
}

static __device__ __forceinline__ float xadd32(float v){ return v + __shfl_xor(v, 32); }

static __device__ __forceinline__ void gload_lds16(const void* g, void* l){
  __builtin_amdgcn_global_load_lds(
      (const __attribute__((address_space(1))) unsigned int*)g,
      (__attribute__((address_space(3))) unsigned int*)l, 16, 0, 0);
}

// ---------------- kernel 1: pack W into MFMA B-fragment order (bf16) ----------------
__global__ void packw_kernel(const float* __restrict__ Wq, const float* __restrict__ Wk,
                             const float* __restrict__ Wv, uint4* __restrict__ Wp){
  int t0 = blockIdx.x * 256 + threadIdx.x;   // 0..12287
  int lane = t0 & 63;
  int grp = t0 >> 6;                          // 0..191
  int w3 = grp >> 6;
  int t  = (grp >> 2) & 15;
  int nc = grp & 3;
  const float* W = (w3 == 0) ? Wq : ((w3 == 1) ? Wk : Wv);
  int g = lane >> 4, cc = lane & 15;
  int k0 = t * 32 + g * 8;
  int n  = nc * 16 + cc;
  uint32_t o[4];
  #pragma unroll
  for (int p = 0; p < 4; ++p){
    float lo = W[(size_t)(k0 + 2*p    ) * DH + n];
    float hi = W[(size_t)(k0 + 2*p + 1) * DH + n];
    o[p] = cvt_pk_bf16(lo, hi);
  }
  Wp[(size_t)grp * 64 + lane] = make_uint4(o[0], o[1], o[2], o[3]);
}

// ---------------- kernel 2: QKV projection (1024 blocks x 16 rows; x staged once in LDS) ----------------
__global__ __launch_bounds__(256, 4) void proj_kernel(
    const float* __restrict__ x, const uint4* __restrict__ Wp,
    const float* __restrict__ bq, const float* __restrict__ bk, const float* __restrict__ bv,
    uint16_t* __restrict__ Qs, uint16_t* __restrict__ Kb, uint16_t* __restrict__ Vt)
{
  __shared__ uint16_t xl[16][520];   // 512 cols + 8 pad
  int tid = threadIdx.x, lane = tid & 63, wv = tid >> 6;
  int c = lane & 15, g = lane >> 4;
  int rowbase = blockIdx.x * 16;

  // stage x tile once: thread handles row=tid>>4, 32 cols starting (tid&15)*32
  {
    int row = tid >> 4, cb = (tid & 15) * 32;
    const float* src = x + (size_t)(rowbase + row) * DIN + cb;
    #pragma unroll
    for (int i = 0; i < 2; ++i){
      float4 f0 = *(const float4*)(src + i * 16 + 0);
      float4 f1 = *(const float4*)(src + i * 16 + 4);
      float4 f2 = *(const float4*)(src + i * 16 + 8);
      float4 f3 = *(const float4*)(src + i * 16 + 12);
      uint4 w0 = make_uint4(cvt_pk_bf16(f0.x, f0.y), cvt_pk_bf16(f0.z, f0.w),
                            cvt_pk_bf16(f1.x, f1.y), cvt_pk_bf16(f1.z, f1.w));
      uint4 w1 = make_uint4(cvt_pk_bf16(f2.x, f2.y), cvt_pk_bf16(f2.z, f2.w),
                            cvt_pk_bf16(f3.x, f3.y), cvt_pk_bf16(f3.z, f3.w));
      *(uint4*)(&xl[row][cb + i * 16]) = w0;
      *(uint4*)(&xl[row][cb + i * 16 + 8]) = w1;
    }
  }
  __syncthreads();

  f32x4 acc[3];
  #pragma unroll
  for (int j = 0; j < 3; ++j)
    #pragma unroll
    for (int r = 0; r < 4; ++r) acc[j][r] = 0.f;

  #pragma unroll 4
  for (int t = 0; t < 16; ++t){
    short8 xa = *(const short8*)(&xl[c][t * 32 + g * 8]);
    #pragma unroll
    for (int j = 0; j < 3; ++j){
      int i = wv * 3 + j;
      union { uint4 u; short8 s; } wf;
      wf.u = Wp[(size_t)((i >> 2) * 64 + t * 4 + (i & 3)) * 64 + lane];
      acc[j] = __builtin_amdgcn_mfma_f32_16x16x32_bf16(xa, wf.s, acc[j], 0, 0, 0);
    }
  }

  int mb0 = rowbase + 4 * g;
  #pragma unroll
  for (int j = 0; j < 3; ++j){
    int i = wv * 3 + j;
    int w3 = i >> 2, nc = i & 3, n = nc * 16 + c;
    const float* B = (w3 == 0) ? bq : ((w3 == 1) ? bk : bv);
    float bias = B[n];
    float v0 = acc[j][0] + bias;
    float v1 = acc[j][1] + bias;
    float v2 = acc[j][2] + bias;
    float v3 = acc[j][3] + bias;
    if (w3 == 0){
      Qs[(size_t)(mb0 + 0) * DH + n] = f2bf(v0 * QSCALE);
      Qs[(size_t)(mb0 + 1) * DH + n] = f2bf(v1 * QSCALE);
      Qs[(size_t)(mb0 + 2) * DH + n] = f2bf(v2 * QSCALE);
      Qs[(size_t)(mb0 + 3) * DH + n] = f2bf(v3 * QSCALE);
    } else if (w3 == 1){
      Kb[(size_t)(mb0 + 0) * DH + n] = f2bf(v0);
      Kb[(size_t)(mb0 + 1) * DH + n] = f2bf(v1);
      Kb[(size_t)(mb0 + 2) * DH + n] = f2bf(v2);
      Kb[(size_t)(mb0 + 3) * DH + n] = f2bf(v3);
    } else {
      int b = mb0 >> 12, mloc = mb0 & 4095;
      uint32_t lo = cvt_pk_bf16(v0, v1);
      uint32_t hi = cvt_pk_bf16(v2, v3);
      *(uint2*)(&Vt[((size_t)(b * DH + n)) * SEQ + mloc]) = make_uint2(lo, hi);
    }
  }
}

// ---------------- kernel 3: flash attention, KV-split=8, 1 q-group, VALU-lean (R5/R11 exact) ----------------
__global__ __launch_bounds__(256, 3) void attn_kernel(
    const uint16_t* __restrict__ Qs, const uint16_t* __restrict__ Kb,
    const uint16_t* __restrict__ Vt, uint16_t* __restrict__ Pacc,
    float* __restrict__ Pl)
{
  __shared__ uint8_t lds[32768];   // [buf][K 8KB | Vt 8KB]
  const int tid = threadIdx.x, lane = tid & 63, wv = tid >> 6;
  const int bid = blockIdx.x;
  const int split = bid & 7, batch = (bid >> 3) & 3, qtile = bid >> 5; // 0..31
  const int c = lane & 31, hi = lane >> 5;
  const int NT = SEQ / NSPLIT / 64;  // 8 tiles of 64 keys

  const int qrow = batch * SEQ + qtile * 128 + wv * 32 + c;

  short8 qf[4];
  {
    const uint16_t* qp = Qs + (size_t)qrow * DH;
    #pragma unroll
    for (int ks = 0; ks < 4; ++ks){
      union { uint4 u; short8 s; } v;
      v.u = *(const uint4*)(qp + ks * 16 + hi * 8);
      qf[ks] = v.s;
    }
  }

  // hoisted swizzled LDS read addresses (shared by K and V paths)
  int addr8[2][4];
  #pragma unroll
  for (int a = 0; a < 2; ++a)
    #pragma unroll
    for (int b = 0; b < 4; ++b)
      addr8[a][b] = (32 * a + c) * 128 + (((2 * b + hi) ^ (c & 7)) << 4);

  // staging source addresses (swizzled source -> linear LDS dest)
  const int slotA = wv * 128 + lane, slotB = slotA + 64;
  const int keyA = slotA >> 3, keyB = slotB >> 3;
  const int dgA = (slotA & 7) ^ (keyA & 7), dgB = (slotB & 7) ^ (keyB & 7);
  const uint8_t* Kg = (const uint8_t*)Kb + ((size_t)(batch * SEQ + split * 512)) * (DH * 2);
  const uint8_t* KgA = Kg + keyA * 128 + dgA * 16;
  const uint8_t* KgB = Kg + keyB * 128 + dgB * 16;
  const uint8_t* Vg = (const uint8_t*)Vt + (size_t)batch * (DH * SEQ * 2) + split * 1024;
  const uint8_t* VgA = Vg + keyA * (SEQ * 2) + dgA * 16;
  const uint8_t* VgB = Vg + keyB * (SEQ * 2) + dgB * 16;

  f32x16 acc[2];
  #pragma unroll
  for (int d = 0; d < 2; ++d)
    #pragma unroll
    for (int r = 0; r < 16; ++r) acc[d][r] = 0.f;

  f32x16 ZERO;
  #pragma unroll
  for (int r = 0; r < 16; ++r) ZERO[r] = 0.f;
  asm volatile("" : "+v"(ZERO));

  float l0_ = 0.f, l1_ = 0.f, l2_ = 0.f, l3_ = 0.f;

  gload_lds16(KgA, lds + wv * 2048);
  gload_lds16(KgB, lds + wv * 2048 + 1024);
  gload_lds16(VgA, lds + 8192 + wv * 2048);
  gload_lds16(VgB, lds + 8192 + wv * 2048 + 1024);
  __syncthreads();

  #pragma unroll 1
  for (int t = 0; t < NT; ++t){
    const int OFF = (t & 1) << 14;
    const int NOFF = OFF ^ 16384;

    if (t < NT - 1){
      gload_lds16(KgA + (size_t)(t + 1) * 8192, lds + NOFF + wv * 2048);
      gload_lds16(KgB + (size_t)(t + 1) * 8192, lds + NOFF + wv * 2048 + 1024);
      gload_lds16(VgA + (size_t)(t + 1) * 128,  lds + NOFF + 8192 + wv * 2048);
      gload_lds16(VgB + (size_t)(t + 1) * 128,  lds + NOFF + 8192 + wv * 2048 + 1024);
    }

    // S^T = K * Q^T; first ks uses ZERO as C
    f32x16 sa[2];
    __builtin_amdgcn_s_setprio(1);
    #pragma unroll
    for (int st = 0; st < 2; ++st){
      #pragma unroll
      for (int ks = 0; ks < 4; ++ks){
        short8 kf = *(const short8*)(lds + OFF + addr8[st][ks]);
        sa[st] = __builtin_amdgcn_mfma_f32_32x32x16_bf16(
            kf, qf[ks], (ks == 0) ? ZERO : sa[st], 0, 0, 0);
      }
    }
    __builtin_amdgcn_s_setprio(0);

    // softmax: raw v_exp_f32 (log2-domain scores), 4-way partial sums
    uint32_t pk[2][8];
    #pragma unroll
    for (int st = 0; st < 2; ++st){
      float pv[16];
      #pragma unroll
      for (int r = 0; r < 16; ++r) pv[r] = __builtin_amdgcn_exp2f(sa[st][r]);
      #pragma unroll
      for (int r = 0; r < 4; ++r){
        l0_ += pv[4 * r + 0];
        l1_ += pv[4 * r + 1];
        l2_ += pv[4 * r + 2];
        l3_ += pv[4 * r + 3];
      }
      #pragma unroll
      for (int p = 0; p < 8; ++p) pk[st][p] = cvt_pk_bf16(pv[2 * p], pv[2 * p + 1]);
    }

    // P^T B-fragments
    short8 pf[4];
    #pragma unroll
    for (int kslab = 0; kslab < 4; ++kslab){
      int st = kslab >> 1, q4 = (kslab & 1) * 4;
      uint32_t w_[4];
      #pragma unroll
      for (int w1 = 0; w1 < 2; ++w1){
        uint32_t a = pk[st][q4 + w1];
        uint32_t b = pk[st][q4 + 2 + w1];
        perm32swap(a, b);
        w_[w1] = a; w_[2 + w1] = b;
      }
      union { uint32_t u[4]; short8 s; } u_;
      u_.u[0] = w_[0]; u_.u[1] = w_[1]; u_.u[2] = w_[2]; u_.u[3] = w_[3];
      pf[kslab] = u_.s;
    }

    // out^T += Vt * P^T
    __builtin_amdgcn_s_setprio(1);
    #pragma unroll
    for (int kslab = 0; kslab < 4; ++kslab){
      #pragma unroll
      for (int dst = 0; dst < 2; ++dst){
        short8 vf = *(const short8*)(lds + OFF + 8192 + addr8[dst][kslab]);
        acc[dst] = __builtin_amdgcn_mfma_f32_32x32x16_bf16(vf, pf[kslab], acc[dst], 0, 0, 0);
      }
    }
    __builtin_amdgcn_s_setprio(0);

    __syncthreads();
  }

  // store bf16 partials
  uint16_t* pa = Pacc + ((size_t)split * 16384 + qrow) * DH;
  #pragma unroll
  for (int dst = 0; dst < 2; ++dst)
    #pragma unroll
    for (int rq = 0; rq < 4; ++rq){
      uint32_t lo = cvt_pk_bf16(acc[dst][rq * 4 + 0], acc[dst][rq * 4 + 1]);
      uint32_t hi2 = cvt_pk_bf16(acc[dst][rq * 4 + 2], acc[dst][rq * 4 + 3]);
      *(uint2*)(pa + dst * 32 + rq * 8 + hi * 4) = make_uint2(lo, hi2);
    }
  float l_tot = xadd32((l0_ + l1_) + (l2_ + l3_));
  if (hi == 0) Pl[(size_t)split * 16384 + qrow] = l_tot;
}

// ---------------- kernel 4: combine the 8 KV-split partials (1024 blocks, 4 d/thread) ----------------
__global__ __launch_bounds__(256) void combine_kernel(
    const uint16_t* __restrict__ Pacc, const float* __restrict__ Pl,
    float* __restrict__ out)
{
  int t = blockIdx.x * 256 + threadIdx.x;    // 0..262143
  int q = t >> 4, part = t & 15;             // 4 d-values each
  float l = 0.f;
  #pragma unroll
  for (int s = 0; s < NSPLIT; ++s) l += Pl[(size_t)s * 16384 + q];
  float inv = 1.0f / l;

  float o[4];
  #pragma unroll
  for (int i = 0; i < 4; ++i) o[i] = 0.f;
  #pragma unroll
  for (int s = 0; s < NSPLIT; ++s){
    const uint16_t* p = Pacc + ((size_t)s * 16384 + q) * DH + part * 4;
    uint2 v = *(const uint2*)(p);
    o[0] += __uint_as_float((v.x & 0xffffu) << 16);
    o[1] += __uint_as_float((v.x >> 16) << 16);
    o[2] += __uint_as_float((v.y & 0xffffu) << 16);
    o[3] += __uint_as_float((v.y >> 16) << 16);
  }
  float4 v = make_float4(o[0] * inv, o[1] * inv, o[2] * inv, o[3] * inv);
  *(float4*)(out + (size_t)q * DH + part * 4) = v;
}

extern "C" void kernel_launch(void* const* d_in, const int* in_sizes, int n_in,
                              void* d_out, int out_size, void* d_ws, size_t ws_size,
                              hipStream_t stream)
{
  (void)in_sizes; (void)n_in; (void)out_size; (void)ws_size;
  const float* x  = (const float*)d_in[0];
  const float* Wq = (const float*)d_in[1];
  const float* bq = (const float*)d_in[2];
  const float* Wk = (const float*)d_in[3];
  const float* bk = (const float*)d_in[4];
  const float* Wv = (const float*)d_in[5];
  const float* bv = (const float*)d_in[6];
  float* out = (float*)d_out;
  uint8_t* ws = (uint8_t*)d_ws;

  const size_t o_Wp = 0;                      // 196608 B
  const size_t o_Q  = 196608;                 // 2 MB bf16 [16384][64]
  const size_t o_K  = o_Q + 2097152;          // 2 MB
  const size_t o_Vt = o_K + 2097152;          // 2 MB bf16 [4][64][4096]
  const size_t o_Pa = o_Vt + 2097152;         // 16 MB bf16 [8][16384][64]
  const size_t o_Pl = o_Pa + 16777216;        // 512 KB f32 [8][16384]

  packw_kernel<<<48, 256, 0, stream>>>(Wq, Wk, Wv, (uint4*)(ws + o_Wp));
  proj_kernel<<<1024, 256, 0, stream>>>(x, (const uint4*)(ws + o_Wp), bq, bk, bv,
      (uint16_t*)(ws + o_Q), (uint16_t*)(ws + o_K), (uint16_t*)(ws + o_Vt));
  attn_kernel<<<1024, 256, 0, stream>>>((const uint16_t*)(ws + o_Q), (const uint16_t*)(ws + o_K),
      (const uint16_t*)(ws + o_Vt), (uint16_t*)(ws + o_Pa), (float*)(ws + o_Pl));
  combine_kernel<<<1024, 256, 0, stream>>>((const uint16_t*)(ws + o_Pa), (const float*)(ws + o_Pl), out);
}